// Round 2
// baseline (1380.611 us; speedup 1.0000x reference)
//
#include <hip/hip_runtime.h>

#define BB 512
#define TT 512
#define FF 64
#define HH 128
#define NCLS 10
#define WT 4            // LDS staging window (steps)
#define CH 16           // producer->consumer chunk (steps)
#define HBP 136         // padded h row (shorts): 272 B, 16B-divisible
#define HBSZ (16 * HBP)

typedef __attribute__((ext_vector_type(8))) short short8;
typedef __attribute__((ext_vector_type(4))) float f32x4;

#define LOG2E 1.4426950408889634f

__device__ __forceinline__ float sigf(float x) {
    return __builtin_amdgcn_rcpf(1.0f + __builtin_amdgcn_exp2f(-LOG2E * x));
}
__device__ __forceinline__ float tanhfast(float x) {
    return 2.0f * __builtin_amdgcn_rcpf(1.0f + __builtin_amdgcn_exp2f(-2.0f * LOG2E * x)) - 1.0f;
}
__device__ __forceinline__ unsigned short f2bf(float f) {
    union { float f; unsigned u; } v; v.f = f;
    unsigned r = v.u + 0x7FFFu + ((v.u >> 16) & 1u);   // RNE
    return (unsigned short)(r >> 16);
}

// LDS-only barrier: drain lgkmcnt + raw s_barrier (no vmcnt drain).
__device__ __forceinline__ void bar_lds() {
    asm volatile("s_waitcnt lgkmcnt(0)" ::: "memory");
    __builtin_amdgcn_s_barrier();
    asm volatile("" ::: "memory");
}

// ---- flag protocol --------------------------------------------------------
__device__ __forceinline__ void wait_flag(int* f) {
    if (threadIdx.x == 0) {
        while (__hip_atomic_load(f, __ATOMIC_ACQUIRE, __HIP_MEMORY_SCOPE_AGENT) == 0)
            __builtin_amdgcn_s_sleep(2);
    }
    __syncthreads();
    (void)__hip_atomic_load(f, __ATOMIC_ACQUIRE, __HIP_MEMORY_SCOPE_AGENT);
}
__device__ __forceinline__ void set_flag(int* f) {
    __threadfence();
    __syncthreads();   // doubles as the per-step publish barrier on chunk-end steps
    if (threadIdx.x == 0)
        __hip_atomic_fetch_add(f, 1, __ATOMIC_RELEASE, __HIP_MEMORY_SCOPE_AGENT);
}

// ---------------------------------------------------------------------------
// R2: K-split 16-wave layer scan. One block = 16 batch rows, 1024 threads.
// Wave pair (w, w+8) computes the SAME 4 gate-tiles (units 16*(w&7)+lm) but
// each half of K (kh = w>>3). After the MFMA loop the pair exchanges partial
// sums via LDS (conflict-free float2 slots) split by accumulator rows:
//   kh=0 finishes rows kb*4+{0,1}, kh=1 finishes rows kb*4+{2,3}.
// -> per-lane epilogue is 2 rows (was 4), B-frags halve (4 waves/SIMD),
//    per-wave MFMA halves. Bias added only in the kh=0 partial.
// ---------------------------------------------------------------------------
template<int XW, bool IS_L1>
__device__ void layer_scan(
    const void* __restrict__ xin_,
    const float* __restrict__ w_ih, const float* __restrict__ w_hh,
    const float* __restrict__ b_ih, const float* __restrict__ b_hh,
    unsigned short* __restrict__ out1,   // L1: h stream out (bf16)
    float* __restrict__ h2s,             // L2: final h out (fp32)
    int* __restrict__ f_in,              // L2: per-chunk input flags
    int* __restrict__ f_out,             // L1: per-chunk done flags
    int bg, unsigned short* xw, unsigned short* hb, float* exch)
{
    const int tid = threadIdx.x;
    const int w = tid >> 6, l = tid & 63, lm = l & 15, kb = l >> 4;
    const int w8 = w & 7, kh = w >> 3;
    const int u = w8 * 16 + lm;          // owned hidden unit
    constexpr int KT  = (XW + HH) / 32;  // 6 (L1) / 8 (L2)
    constexpr int KTH = KT / 2;          // per-wave K-half: 3 / 4
    constexpr int XKT = XW / 32;         // 2 / 4
    constexpr int XWP = XW + 8;          // padded LDS row (shorts)
    constexpr int XBUF = WT * 16 * XWP;  // one window buffer (shorts)

    const int ktbase = kh * KTH;
    const int rbase  = kb * 4 + kh * 2;  // first of this lane's 2 output rows

    // --- stationary B fragments + bias (kh half only): gate g = j*128 + u ---
    short8 bf[4][KTH];
    float bv[4];
    #pragma unroll
    for (int j = 0; j < 4; j++) {
        const int g = j * 128 + u;
        bv[j] = (kh == 0) ? (b_ih[g] + b_hh[g]) : 0.0f;
        #pragma unroll
        for (int ktl = 0; ktl < KTH; ktl++) {
            const int kt = ktbase + ktl;
            const int k0 = kt * 32 + kb * 8;
            const float* s = (k0 < XW) ? (w_ih + (size_t)g * XW + k0)
                                       : (w_hh + (size_t)g * HH + (k0 - XW));
            short8 t;
            #pragma unroll
            for (int q = 0; q < 8; q++) t[q] = (short)f2bf(s[q]);
            bf[j][ktl] = t;
        }
    }

    for (int i = tid; i < 2 * HBSZ; i += 1024) hb[i] = 0;

    float c[2] = {0.f, 0.f}, hlast[2] = {0.f, 0.f};

    // --- prefetch window 0 into registers (1024 threads -> one vec each) ---
    float4 pfa;          // L1: 4 fp32
    uint4  pf0;          // L2: 8 bf16
    if (IS_L1) {
        const float* x = (const float*)xin_;
        const int flat = tid * 4;
        const int tt = flat >> 10, row = (flat >> 6) & 15, k = flat & 63;
        pfa = *(const float4*)(x + (((size_t)(bg * 16 + row)) * TT + tt) * FF + k);
    } else {
        wait_flag(&f_in[0]);
        const unsigned short* o1 = (const unsigned short*)xin_;
        const int flat = tid * 8;
        const int tt = flat >> 11, row = (flat >> 7) & 15, k = flat & 127;
        pf0 = *(const uint4*)(o1 + (((size_t)(bg * 16 + row)) * TT + tt) * HH + k);
    }

    for (int tl = 0; tl < TT; tl++) {
        if ((tl & (WT - 1)) == 0) {
            // commit prefetched window to LDS
            unsigned short* buf = xw + ((tl >> 2) & 1) * XBUF;
            if (IS_L1) {
                const int flat = tid * 4;
                const int tt = flat >> 10, row = (flat >> 6) & 15, k = flat & 63;
                uint2 pv;
                pv.x = (unsigned)f2bf(pfa.x) | ((unsigned)f2bf(pfa.y) << 16);
                pv.y = (unsigned)f2bf(pfa.z) | ((unsigned)f2bf(pfa.w) << 16);
                *(uint2*)&buf[(tt * 16 + row) * XWP + k] = pv;
            } else {
                const int flat = tid * 8;
                const int tt = flat >> 11, row = (flat >> 7) & 15, k = flat & 127;
                *(uint4*)&buf[(tt * 16 + row) * XWP + k] = pf0;
            }
            bar_lds();
            // issue prefetch for next window
            const int wst = tl + WT;
            if (wst < TT) {
                if (!IS_L1 && (wst & (CH - 1)) == 0) wait_flag(&f_in[wst >> 4]);
                if (IS_L1) {
                    const float* x = (const float*)xin_;
                    const int flat = tid * 4;
                    const int tt = flat >> 10, row = (flat >> 6) & 15, k = flat & 63;
                    pfa = *(const float4*)(x + (((size_t)(bg * 16 + row)) * TT + wst + tt) * FF + k);
                } else {
                    const unsigned short* o1 = (const unsigned short*)xin_;
                    const int flat = tid * 8;
                    const int tt = flat >> 11, row = (flat >> 7) & 15, k = flat & 127;
                    pf0 = *(const uint4*)(o1 + (((size_t)(bg * 16 + row)) * TT + wst + tt) * HH + k);
                }
            }
        }
        const int tloc = tl & (WT - 1);
        const unsigned short* abase = xw + ((tl >> 2) & 1) * XBUF
                                    + (tloc * 16 + lm) * XWP + kb * 8;
        const unsigned short* hbase = hb + (tl & 1) * HBSZ + lm * HBP + kb * 8;

        f32x4 a0 = {bv[0], bv[0], bv[0], bv[0]};
        f32x4 a1 = {bv[1], bv[1], bv[1], bv[1]};
        f32x4 a2 = {bv[2], bv[2], bv[2], bv[2]};
        f32x4 a3 = {bv[3], bv[3], bv[3], bv[3]};
        #pragma unroll
        for (int ktl = 0; ktl < KTH; ktl++) {
            const int kt = ktbase + ktl;
            const unsigned short* ap = (kt < XKT) ? (abase + kt * 32)
                                                  : (hbase + (kt - XKT) * 32);
            const short8 a = *(const short8*)ap;
            a0 = __builtin_amdgcn_mfma_f32_16x16x32_bf16(a, bf[0][ktl], a0, 0, 0, 0);
            a1 = __builtin_amdgcn_mfma_f32_16x16x32_bf16(a, bf[1][ktl], a1, 0, 0, 0);
            a2 = __builtin_amdgcn_mfma_f32_16x16x32_bf16(a, bf[2][ktl], a2, 0, 0, 0);
            a3 = __builtin_amdgcn_mfma_f32_16x16x32_bf16(a, bf[3][ktl], a3, 0, 0, 0);
        }

        // ---- K-half partial-sum exchange (conflict-free: lane-stride 8B) ----
        // exLO[j][w8*64+l] holds regs {0,1} from kh=1; exHI holds {2,3} from kh=0.
        const int eslot = (w8 * 64 + l) * 2;
        float* exLO = exch;
        float* exHI = exch + 4096;
        if (kh) {
            *(float2*)&exLO[eslot       ] = make_float2(a0[0], a0[1]);
            *(float2*)&exLO[eslot + 1024] = make_float2(a1[0], a1[1]);
            *(float2*)&exLO[eslot + 2048] = make_float2(a2[0], a2[1]);
            *(float2*)&exLO[eslot + 3072] = make_float2(a3[0], a3[1]);
        } else {
            *(float2*)&exHI[eslot       ] = make_float2(a0[2], a0[3]);
            *(float2*)&exHI[eslot + 1024] = make_float2(a1[2], a1[3]);
            *(float2*)&exHI[eslot + 2048] = make_float2(a2[2], a2[3]);
            *(float2*)&exHI[eslot + 3072] = make_float2(a3[2], a3[3]);
        }
        bar_lds();
        float vA[4], vB[4];   // gates for rows rbase+0 / rbase+1
        if (kh == 0) {
            float2 p;
            p = *(const float2*)&exLO[eslot       ]; vA[0] = a0[0] + p.x; vB[0] = a0[1] + p.y;
            p = *(const float2*)&exLO[eslot + 1024]; vA[1] = a1[0] + p.x; vB[1] = a1[1] + p.y;
            p = *(const float2*)&exLO[eslot + 2048]; vA[2] = a2[0] + p.x; vB[2] = a2[1] + p.y;
            p = *(const float2*)&exLO[eslot + 3072]; vA[3] = a3[0] + p.x; vB[3] = a3[1] + p.y;
        } else {
            float2 p;
            p = *(const float2*)&exHI[eslot       ]; vA[0] = a0[2] + p.x; vB[0] = a0[3] + p.y;
            p = *(const float2*)&exHI[eslot + 1024]; vA[1] = a1[2] + p.x; vB[1] = a1[3] + p.y;
            p = *(const float2*)&exHI[eslot + 2048]; vA[2] = a2[2] + p.x; vB[2] = a2[3] + p.y;
            p = *(const float2*)&exHI[eslot + 3072]; vA[3] = a3[2] + p.x; vB[3] = a3[3] + p.y;
        }

        // ---- in-lane epilogue: unit u, rows rbase+0 / rbase+1 ----
        {
            const float iv = sigf(vA[0]);
            const float fv = sigf(vA[1]);
            const float gv = tanhfast(vA[2]);
            const float ov = sigf(vA[3]);
            c[0] = fv * c[0] + iv * gv;
            const float h = ov * tanhfast(c[0]);
            hlast[0] = h;
            const unsigned short h16 = f2bf(h);
            hb[((tl + 1) & 1) * HBSZ + (rbase + 0) * HBP + u] = h16;
            if (IS_L1)
                out1[(((size_t)(bg * 16 + rbase + 0)) * TT + tl) * HH + u] = h16;
        }
        {
            const float iv = sigf(vB[0]);
            const float fv = sigf(vB[1]);
            const float gv = tanhfast(vB[2]);
            const float ov = sigf(vB[3]);
            c[1] = fv * c[1] + iv * gv;
            const float h = ov * tanhfast(c[1]);
            hlast[1] = h;
            const unsigned short h16 = f2bf(h);
            hb[((tl + 1) & 1) * HBSZ + (rbase + 1) * HBP + u] = h16;
            if (IS_L1)
                out1[(((size_t)(bg * 16 + rbase + 1)) * TT + tl) * HH + u] = h16;
        }

        if (IS_L1 && (tl & (CH - 1)) == (CH - 1)) {
            set_flag(&f_out[tl >> 4]);   // fence + barrier + flag (per chunk)
        } else {
            bar_lds();                   // publish h for next step
        }
    }

    if (!IS_L1) {
        h2s[((size_t)(bg * 16 + rbase + 0)) * HH + u] = hlast[0];
        h2s[((size_t)(bg * 16 + rbase + 1)) * HH + u] = hlast[1];
    }
}

// bid 0-31: layer-1 scan (producer). bid 32-63: layer-2 scan (consumer).
// bid and bid+32 share bid%8 -> same XCD for out1 L2-cache locality.
__global__ __launch_bounds__(1024, 4) void lstm_pipe(
    const float* __restrict__ x,
    const float* __restrict__ w1_ih, const float* __restrict__ w1_hh,
    const float* __restrict__ b1_ih, const float* __restrict__ b1_hh,
    const float* __restrict__ w2_ih, const float* __restrict__ w2_hh,
    const float* __restrict__ b2_ih, const float* __restrict__ b2_hh,
    unsigned short* __restrict__ out1, float* __restrict__ h2s,
    int* __restrict__ flags)
{
    __shared__ __align__(16) unsigned short xw[2 * WT * 16 * (HH + 8)]; // 34816 B
    __shared__ __align__(16) unsigned short hb[2 * HBSZ];               //  8704 B
    __shared__ __align__(16) float exch[8192];                          // 32768 B
    const int bid = blockIdx.x;
    if (bid < 32)
        layer_scan<FF, true >(x, w1_ih, w1_hh, b1_ih, b1_hh, out1, nullptr,
                              nullptr, &flags[bid * 32], bid, xw, hb, exch);
    else
        layer_scan<HH, false>(out1, w2_ih, w2_hh, b2_ih, b2_hh, nullptr, h2s,
                              &flags[(bid - 32) * 32], nullptr, bid - 32, xw, hb, exch);
}

__global__ void final_kernel(const float* __restrict__ h2s,
                             const float* __restrict__ w_fc,
                             const float* __restrict__ b_fc,
                             float* __restrict__ out)
{
    const int idx = blockIdx.x * blockDim.x + threadIdx.x;
    if (idx >= BB * NCLS) return;
    const int b = idx / NCLS, cls = idx % NCLS;
    const float* hp = h2s + (size_t)b * HH;
    const float* wp = w_fc + (size_t)cls * HH;
    float acc = b_fc[cls];
    #pragma unroll 8
    for (int k = 0; k < HH; k++) acc += hp[k] * wp[k];
    out[idx] = sigf(acc);
}

extern "C" void kernel_launch(void* const* d_in, const int* in_sizes, int n_in,
                              void* d_out, int out_size, void* d_ws, size_t ws_size,
                              hipStream_t stream)
{
    const float* x     = (const float*)d_in[0];
    const float* w1_ih = (const float*)d_in[1];
    const float* w1_hh = (const float*)d_in[2];
    const float* b1_ih = (const float*)d_in[3];
    const float* b1_hh = (const float*)d_in[4];
    const float* w2_ih = (const float*)d_in[5];
    const float* w2_hh = (const float*)d_in[6];
    const float* b2_ih = (const float*)d_in[7];
    const float* b2_hh = (const float*)d_in[8];
    const float* w_fc  = (const float*)d_in[9];
    const float* b_fc  = (const float*)d_in[10];
    float* out = (float*)d_out;

    // workspace: [h2s fp32 256KB | flags 4KB | out1 bf16 67MB]
    char* ws = (char*)d_ws;
    float* h2s = (float*)ws;                 ws += (size_t)BB * HH * sizeof(float);
    int* flags = (int*)ws;                   ws += 32 * 32 * sizeof(int);
    unsigned short* out1 = (unsigned short*)ws;

    hipMemsetAsync(flags, 0, 32 * 32 * sizeof(int), stream);
    lstm_pipe<<<64, 1024, 0, stream>>>(x, w1_ih, w1_hh, b1_ih, b1_hh,
                                       w2_ih, w2_hh, b2_ih, b2_hh,
                                       out1, h2s, flags);
    final_kernel<<<(BB * NCLS + 255) / 256, 256, 0, stream>>>(h2s, w_fc, b_fc, out);
}

// Round 3
// 1283.536 us; speedup vs baseline: 1.0756x; 1.0756x over previous
//
#include <hip/hip_runtime.h>

#define BB 512
#define TT 512
#define FF 64
#define HH 128
#define NCLS 10
#define WT 4            // LDS staging window (steps)
#define CH 16           // producer->consumer chunk (steps)
#define HBP 136         // padded h row (shorts): 272 B, 16B-divisible
#define HBSZ (16 * HBP)

typedef __attribute__((ext_vector_type(8))) short short8;
typedef __attribute__((ext_vector_type(4))) float f32x4;

#define LOG2E 1.4426950408889634f

__device__ __forceinline__ float sigf(float x) {
    return __builtin_amdgcn_rcpf(1.0f + __builtin_amdgcn_exp2f(-LOG2E * x));
}
__device__ __forceinline__ float tanhfast(float x) {
    return 2.0f * __builtin_amdgcn_rcpf(1.0f + __builtin_amdgcn_exp2f(-2.0f * LOG2E * x)) - 1.0f;
}
__device__ __forceinline__ unsigned short f2bf(float f) {
    union { float f; unsigned u; } v; v.f = f;
    unsigned r = v.u + 0x7FFFu + ((v.u >> 16) & 1u);   // RNE
    return (unsigned short)(r >> 16);
}

// LDS-only barrier: drain lgkmcnt + raw s_barrier (no vmcnt drain).
__device__ __forceinline__ void bar_lds() {
    asm volatile("s_waitcnt lgkmcnt(0)" ::: "memory");
    __builtin_amdgcn_s_barrier();
    asm volatile("" ::: "memory");
}

// ---- flag protocol --------------------------------------------------------
__device__ __forceinline__ void wait_flag(int* f) {
    if (threadIdx.x == 0) {
        while (__hip_atomic_load(f, __ATOMIC_ACQUIRE, __HIP_MEMORY_SCOPE_AGENT) == 0)
            __builtin_amdgcn_s_sleep(2);
    }
    __syncthreads();
    (void)__hip_atomic_load(f, __ATOMIC_ACQUIRE, __HIP_MEMORY_SCOPE_AGENT);
}
__device__ __forceinline__ void set_flag(int* f) {
    __threadfence();
    __syncthreads();   // doubles as the per-step publish barrier on chunk-end steps
    if (threadIdx.x == 0)
        __hip_atomic_fetch_add(f, 1, __ATOMIC_RELEASE, __HIP_MEMORY_SCOPE_AGENT);
}

// ---------------------------------------------------------------------------
// R3: R1 per-step structure, but each block carries TWO independent 16-row
// sequences (seq 0: rows bg*32..+15, seq 1: rows bg*32+16..+31). Weights are
// shared; accumulators/state/LDS duplicated. The two dependency chains
// interleave inside each wave -> latency stalls (barrier skew, LDS h-publish,
// transcendental chains) are hidden by the sibling sequence's instructions.
// Exactly ONE barrier per step, as in R1 (R2 lesson: never lengthen the
// serial barrier-to-barrier chain).
// ---------------------------------------------------------------------------
template<int XW, bool IS_L1>
__device__ void layer_scan(
    const void* __restrict__ xin_,
    const float* __restrict__ w_ih, const float* __restrict__ w_hh,
    const float* __restrict__ b_ih, const float* __restrict__ b_hh,
    unsigned short* __restrict__ out1,   // L1: h stream out (bf16)
    float* __restrict__ h2s,             // L2: final h out (fp32)
    int* __restrict__ f_in,              // L2: per-chunk input flags
    int* __restrict__ f_out,             // L1: per-chunk done flags
    int bg, unsigned short* xw, unsigned short* hb)
{
    const int tid = threadIdx.x;
    const int w = tid >> 6, l = tid & 63, lm = l & 15, kb = l >> 4;
    const int u = w * 16 + lm;           // owned hidden unit
    constexpr int KT  = (XW + HH) / 32;  // 6 (L1) / 8 (L2)
    constexpr int XKT = XW / 32;         // 2 / 4
    constexpr int XWP = XW + 8;          // padded LDS row (shorts)
    constexpr int XBUF = WT * 16 * XWP;  // one window buffer (shorts)

    // --- stationary B fragments + bias (SHARED between both sequences) ---
    short8 bf[4][KT];
    float bv[4];
    #pragma unroll
    for (int j = 0; j < 4; j++) {
        const int g = j * 128 + u;
        bv[j] = b_ih[g] + b_hh[g];
        #pragma unroll
        for (int kt = 0; kt < KT; kt++) {
            const int k0 = kt * 32 + kb * 8;
            const float* s = (k0 < XW) ? (w_ih + (size_t)g * XW + k0)
                                       : (w_hh + (size_t)g * HH + (k0 - XW));
            short8 t;
            #pragma unroll
            for (int q = 0; q < 8; q++) t[q] = (short)f2bf(s[q]);
            bf[j][kt] = t;
        }
    }

    for (int i = tid; i < 4 * HBSZ; i += 512) hb[i] = 0;   // 2 seqs x 2 buffers

    float c[2][4] = {{0.f,0.f,0.f,0.f},{0.f,0.f,0.f,0.f}};
    float hlast[2][4] = {{0.f,0.f,0.f,0.f},{0.f,0.f,0.f,0.f}};

    // --- prefetch window 0 into registers, per sequence ---
    float4 pfa[2], pfb[2];     // L1: 8 fp32 per seq
    uint4  pf0[2], pf1[2];     // L2: 16 bf16 per seq
    if (IS_L1) {
        const float* x = (const float*)xin_;
        const int flat = tid * 8;
        const int tt = flat >> 10, row = (flat >> 6) & 15, k = flat & 63;
        #pragma unroll
        for (int s = 0; s < 2; s++) {
            const float* sp = x + (((size_t)(bg * 32 + s * 16 + row)) * TT + tt) * FF + k;
            pfa[s] = *(const float4*)sp; pfb[s] = *(const float4*)(sp + 4);
        }
    } else {
        wait_flag(&f_in[0]);
        const unsigned short* o1 = (const unsigned short*)xin_;
        const int flat = tid * 16;
        const int tt = flat >> 11, row = (flat >> 7) & 15, k = flat & 127;
        #pragma unroll
        for (int s = 0; s < 2; s++) {
            const unsigned short* sp = o1 + (((size_t)(bg * 32 + s * 16 + row)) * TT + tt) * HH + k;
            pf0[s] = *(const uint4*)sp; pf1[s] = *(const uint4*)(sp + 8);
        }
    }

    for (int tl = 0; tl < TT; tl++) {
        if ((tl & (WT - 1)) == 0) {
            // commit prefetched windows to LDS (both sequences)
            if (IS_L1) {
                const int flat = tid * 8;
                const int tt = flat >> 10, row = (flat >> 6) & 15, k = flat & 63;
                #pragma unroll
                for (int s = 0; s < 2; s++) {
                    unsigned short* buf = xw + s * 2 * XBUF + ((tl >> 2) & 1) * XBUF;
                    uint4 pv;
                    pv.x = (unsigned)f2bf(pfa[s].x) | ((unsigned)f2bf(pfa[s].y) << 16);
                    pv.y = (unsigned)f2bf(pfa[s].z) | ((unsigned)f2bf(pfa[s].w) << 16);
                    pv.z = (unsigned)f2bf(pfb[s].x) | ((unsigned)f2bf(pfb[s].y) << 16);
                    pv.w = (unsigned)f2bf(pfb[s].z) | ((unsigned)f2bf(pfb[s].w) << 16);
                    *(uint4*)&buf[(tt * 16 + row) * XWP + k] = pv;
                }
            } else {
                const int flat = tid * 16;
                const int tt = flat >> 11, row = (flat >> 7) & 15, k = flat & 127;
                #pragma unroll
                for (int s = 0; s < 2; s++) {
                    unsigned short* buf = xw + s * 2 * XBUF + ((tl >> 2) & 1) * XBUF;
                    *(uint4*)&buf[(tt * 16 + row) * XWP + k]     = pf0[s];
                    *(uint4*)&buf[(tt * 16 + row) * XWP + k + 8] = pf1[s];
                }
            }
            bar_lds();
            // issue prefetch for next window (both sequences)
            const int wst = tl + WT;
            if (wst < TT) {
                if (!IS_L1 && (wst & (CH - 1)) == 0) wait_flag(&f_in[wst >> 4]);
                if (IS_L1) {
                    const float* x = (const float*)xin_;
                    const int flat = tid * 8;
                    const int tt = flat >> 10, row = (flat >> 6) & 15, k = flat & 63;
                    #pragma unroll
                    for (int s = 0; s < 2; s++) {
                        const float* sp = x + (((size_t)(bg * 32 + s * 16 + row)) * TT + wst + tt) * FF + k;
                        pfa[s] = *(const float4*)sp; pfb[s] = *(const float4*)(sp + 4);
                    }
                } else {
                    const unsigned short* o1 = (const unsigned short*)xin_;
                    const int flat = tid * 16;
                    const int tt = flat >> 11, row = (flat >> 7) & 15, k = flat & 127;
                    #pragma unroll
                    for (int s = 0; s < 2; s++) {
                        const unsigned short* sp = o1 + (((size_t)(bg * 32 + s * 16 + row)) * TT + wst + tt) * HH + k;
                        pf0[s] = *(const uint4*)sp; pf1[s] = *(const uint4*)(sp + 8);
                    }
                }
            }
        }
        const int tloc = tl & (WT - 1);

        // ---- MFMA: two independent accumulator sets ----
        f32x4 ac[2][4];
        #pragma unroll
        for (int s = 0; s < 2; s++)
            #pragma unroll
            for (int j = 0; j < 4; j++)
                ac[s][j] = (f32x4){bv[j], bv[j], bv[j], bv[j]};

        #pragma unroll
        for (int s = 0; s < 2; s++) {
            const unsigned short* abase = xw + s * 2 * XBUF + ((tl >> 2) & 1) * XBUF
                                        + (tloc * 16 + lm) * XWP + kb * 8;
            const unsigned short* hbase = hb + s * 2 * HBSZ + (tl & 1) * HBSZ
                                        + lm * HBP + kb * 8;
            #pragma unroll
            for (int kt = 0; kt < KT; kt++) {
                const unsigned short* ap = (kt < XKT) ? (abase + kt * 32)
                                                      : (hbase + (kt - XKT) * 32);
                const short8 a = *(const short8*)ap;
                ac[s][0] = __builtin_amdgcn_mfma_f32_16x16x32_bf16(a, bf[0][kt], ac[s][0], 0, 0, 0);
                ac[s][1] = __builtin_amdgcn_mfma_f32_16x16x32_bf16(a, bf[1][kt], ac[s][1], 0, 0, 0);
                ac[s][2] = __builtin_amdgcn_mfma_f32_16x16x32_bf16(a, bf[2][kt], ac[s][2], 0, 0, 0);
                ac[s][3] = __builtin_amdgcn_mfma_f32_16x16x32_bf16(a, bf[3][kt], ac[s][3], 0, 0, 0);
            }
        }

        // ---- in-lane epilogue: unit u, rows kb*4+r, both sequences ----
        #pragma unroll
        for (int s = 0; s < 2; s++) {
            #pragma unroll
            for (int r = 0; r < 4; r++) {
                const float iv = sigf(ac[s][0][r]);
                const float fv = sigf(ac[s][1][r]);
                const float gv = tanhfast(ac[s][2][r]);
                const float ov = sigf(ac[s][3][r]);
                c[s][r] = fv * c[s][r] + iv * gv;
                const float h = ov * tanhfast(c[s][r]);
                hlast[s][r] = h;
                const unsigned short h16 = f2bf(h);
                hb[s * 2 * HBSZ + ((tl + 1) & 1) * HBSZ + (kb * 4 + r) * HBP + u] = h16;
                if (IS_L1)
                    out1[(((size_t)(bg * 32 + s * 16 + kb * 4 + r)) * TT + tl) * HH + u] = h16;
            }
        }

        if (IS_L1 && (tl & (CH - 1)) == (CH - 1)) {
            set_flag(&f_out[tl >> 4]);   // fence + barrier + flag (per chunk)
        } else {
            bar_lds();                   // publish h for next step
        }
    }

    if (!IS_L1) {
        #pragma unroll
        for (int s = 0; s < 2; s++)
            #pragma unroll
            for (int r = 0; r < 4; r++)
                h2s[((size_t)(bg * 32 + s * 16 + kb * 4 + r)) * HH + u] = hlast[s][r];
    }
}

// bid 0-15: layer-1 scan (producer, 32 rows each). bid 16-31: layer-2 scan.
// bid and bid+16 share bid%8 -> same XCD for out1 L2-cache locality.
__global__ __launch_bounds__(512, 1) void lstm_pipe(
    const float* __restrict__ x,
    const float* __restrict__ w1_ih, const float* __restrict__ w1_hh,
    const float* __restrict__ b1_ih, const float* __restrict__ b1_hh,
    const float* __restrict__ w2_ih, const float* __restrict__ w2_hh,
    const float* __restrict__ b2_ih, const float* __restrict__ b2_hh,
    unsigned short* __restrict__ out1, float* __restrict__ h2s,
    int* __restrict__ flags)
{
    __shared__ __align__(16) unsigned short xw[4 * WT * 16 * (HH + 8)]; // 69632 B
    __shared__ __align__(16) unsigned short hb[4 * HBSZ];               // 17408 B
    const int bid = blockIdx.x;
    if (bid < 16)
        layer_scan<FF, true >(x, w1_ih, w1_hh, b1_ih, b1_hh, out1, nullptr,
                              nullptr, &flags[bid * 32], bid, xw, hb);
    else
        layer_scan<HH, false>(out1, w2_ih, w2_hh, b2_ih, b2_hh, nullptr, h2s,
                              &flags[(bid - 16) * 32], nullptr, bid - 16, xw, hb);
}

__global__ void final_kernel(const float* __restrict__ h2s,
                             const float* __restrict__ w_fc,
                             const float* __restrict__ b_fc,
                             float* __restrict__ out)
{
    const int idx = blockIdx.x * blockDim.x + threadIdx.x;
    if (idx >= BB * NCLS) return;
    const int b = idx / NCLS, cls = idx % NCLS;
    const float* hp = h2s + (size_t)b * HH;
    const float* wp = w_fc + (size_t)cls * HH;
    float acc = b_fc[cls];
    #pragma unroll 8
    for (int k = 0; k < HH; k++) acc += hp[k] * wp[k];
    out[idx] = sigf(acc);
}

extern "C" void kernel_launch(void* const* d_in, const int* in_sizes, int n_in,
                              void* d_out, int out_size, void* d_ws, size_t ws_size,
                              hipStream_t stream)
{
    const float* x     = (const float*)d_in[0];
    const float* w1_ih = (const float*)d_in[1];
    const float* w1_hh = (const float*)d_in[2];
    const float* b1_ih = (const float*)d_in[3];
    const float* b1_hh = (const float*)d_in[4];
    const float* w2_ih = (const float*)d_in[5];
    const float* w2_hh = (const float*)d_in[6];
    const float* b2_ih = (const float*)d_in[7];
    const float* b2_hh = (const float*)d_in[8];
    const float* w_fc  = (const float*)d_in[9];
    const float* b_fc  = (const float*)d_in[10];
    float* out = (float*)d_out;

    // workspace: [h2s fp32 256KB | flags 2KB | out1 bf16 67MB]
    char* ws = (char*)d_ws;
    float* h2s = (float*)ws;                 ws += (size_t)BB * HH * sizeof(float);
    int* flags = (int*)ws;                   ws += 16 * 32 * sizeof(int);
    unsigned short* out1 = (unsigned short*)ws;

    hipMemsetAsync(flags, 0, 16 * 32 * sizeof(int), stream);
    lstm_pipe<<<32, 512, 0, stream>>>(x, w1_ih, w1_hh, b1_ih, b1_hh,
                                      w2_ih, w2_hh, b2_ih, b2_hh,
                                      out1, h2s, flags);
    final_kernel<<<(BB * NCLS + 255) / 256, 256, 0, stream>>>(h2s, w_fc, b_fc, out);
}

// Round 4
// 884.659 us; speedup vs baseline: 1.5606x; 1.4509x over previous
//
#include <hip/hip_runtime.h>

#define BB 512
#define TT 512
#define FF 64
#define HH 128
#define NCLS 10
#define WT 4            // LDS staging window (steps)
#define CH 16           // producer->consumer chunk (steps)
#define HBP 136         // padded h row (shorts): 272 B, 16B-divisible
#define HBSZ (16 * HBP)

typedef __attribute__((ext_vector_type(8))) short short8;
typedef __attribute__((ext_vector_type(4))) float f32x4;

#define LOG2E 1.4426950408889634f

__device__ __forceinline__ float sigf(float x) {
    return __builtin_amdgcn_rcpf(1.0f + __builtin_amdgcn_exp2f(-LOG2E * x));
}
__device__ __forceinline__ float tanhfast(float x) {
    return 2.0f * __builtin_amdgcn_rcpf(1.0f + __builtin_amdgcn_exp2f(-2.0f * LOG2E * x)) - 1.0f;
}
__device__ __forceinline__ unsigned short f2bf(float f) {
    union { float f; unsigned u; } v; v.f = f;
    unsigned r = v.u + 0x7FFFu + ((v.u >> 16) & 1u);   // RNE
    return (unsigned short)(r >> 16);
}

// LDS-only barrier: drain lgkmcnt + raw s_barrier (no vmcnt drain).
__device__ __forceinline__ void bar_lds() {
    asm volatile("s_waitcnt lgkmcnt(0)" ::: "memory");
    __builtin_amdgcn_s_barrier();
    asm volatile("" ::: "memory");
}

// ---- flag protocol --------------------------------------------------------
__device__ __forceinline__ void wait_flag(int* f) {
    if (threadIdx.x == 0) {
        while (__hip_atomic_load(f, __ATOMIC_ACQUIRE, __HIP_MEMORY_SCOPE_AGENT) == 0)
            __builtin_amdgcn_s_sleep(2);
    }
    __syncthreads();
    (void)__hip_atomic_load(f, __ATOMIC_ACQUIRE, __HIP_MEMORY_SCOPE_AGENT);
}
__device__ __forceinline__ void set_flag(int* f) {
    __threadfence();
    __syncthreads();   // doubles as the per-step publish barrier on chunk-end steps
    if (threadIdx.x == 0)
        __hip_atomic_fetch_add(f, 1, __ATOMIC_RELEASE, __HIP_MEMORY_SCOPE_AGENT);
}

// ---------------------------------------------------------------------------
// R4: R1 structure + x-burst. The x-half of the gate GEMM (no h dependence)
// is computed in 2-step register bursts from the staged LDS window, so the
// serial per-step path is only: barrier -> 4 h-k-tiles (ds_read+MFMA) ->
// epilogue -> barrier. Per-step LDS read traffic halves (the R3-measured
// ~2000cyc fixed stall = post-barrier LDS port serialization, 8 waves all
// re-reading the full A tile). Accumulation order (bias, x-tiles, h-tiles)
// is bit-identical to R1. Window loop fully unrolled -> xacc / h-parity
// indices are compile-time (no scratch).
// ---------------------------------------------------------------------------
template<int XW, bool IS_L1>
__device__ void layer_scan(
    const void* __restrict__ xin_,
    const float* __restrict__ w_ih, const float* __restrict__ w_hh,
    const float* __restrict__ b_ih, const float* __restrict__ b_hh,
    unsigned short* __restrict__ out1,   // L1: h stream out (bf16)
    float* __restrict__ h2s,             // L2: final h out (fp32)
    int* __restrict__ f_in,              // L2: per-chunk input flags
    int* __restrict__ f_out,             // L1: per-chunk done flags
    int bg, unsigned short* xw, unsigned short* hb)
{
    const int tid = threadIdx.x;
    const int w = tid >> 6, l = tid & 63, lm = l & 15, kb = l >> 4;
    const int u = w * 16 + lm;           // owned hidden unit
    constexpr int KT  = (XW + HH) / 32;  // 6 (L1) / 8 (L2)
    constexpr int XKT = XW / 32;         // 2 / 4
    constexpr int HKT = HH / 32;         // 4 (both layers)
    constexpr int XWP = XW + 8;          // padded LDS row (shorts)
    constexpr int XBUF = WT * 16 * XWP;  // one window buffer (shorts)

    // --- stationary B fragments + bias: gate g = j*128 + u; x-kts then h-kts ---
    short8 bf[4][KT];
    float bv[4];
    #pragma unroll
    for (int j = 0; j < 4; j++) {
        const int g = j * 128 + u;
        bv[j] = b_ih[g] + b_hh[g];
        #pragma unroll
        for (int kt = 0; kt < KT; kt++) {
            const int k0 = kt * 32 + kb * 8;
            const float* s = (k0 < XW) ? (w_ih + (size_t)g * XW + k0)
                                       : (w_hh + (size_t)g * HH + (k0 - XW));
            short8 t;
            #pragma unroll
            for (int q = 0; q < 8; q++) t[q] = (short)f2bf(s[q]);
            bf[j][kt] = t;
        }
    }

    for (int i = tid; i < 2 * HBSZ; i += 512) hb[i] = 0;

    float c[4] = {0.f, 0.f, 0.f, 0.f}, hlast[4] = {0.f, 0.f, 0.f, 0.f};

    // --- prefetch window 0 into registers ---
    float4 pfa, pfb;     // L1: 8 fp32
    uint4  pf0, pf1;     // L2: 16 bf16
    if (IS_L1) {
        const float* x = (const float*)xin_;
        const int flat = tid * 8;
        const int tt = flat >> 10, row = (flat >> 6) & 15, k = flat & 63;
        const float* s = x + (((size_t)(bg * 16 + row)) * TT + tt) * FF + k;
        pfa = *(const float4*)s; pfb = *(const float4*)(s + 4);
    } else {
        wait_flag(&f_in[0]);
        const unsigned short* o1 = (const unsigned short*)xin_;
        const int flat = tid * 16;
        const int tt = flat >> 11, row = (flat >> 7) & 15, k = flat & 127;
        const unsigned short* s = o1 + (((size_t)(bg * 16 + row)) * TT + tt) * HH + k;
        pf0 = *(const uint4*)s; pf1 = *(const uint4*)(s + 8);
    }

    for (int tw = 0; tw < TT; tw += WT) {
        // ---- commit prefetched window to LDS ----
        unsigned short* buf = xw + ((tw >> 2) & 1) * XBUF;
        if (IS_L1) {
            const int flat = tid * 8;
            const int tt = flat >> 10, row = (flat >> 6) & 15, k = flat & 63;
            uint4 pv;
            pv.x = (unsigned)f2bf(pfa.x) | ((unsigned)f2bf(pfa.y) << 16);
            pv.y = (unsigned)f2bf(pfa.z) | ((unsigned)f2bf(pfa.w) << 16);
            pv.z = (unsigned)f2bf(pfb.x) | ((unsigned)f2bf(pfb.y) << 16);
            pv.w = (unsigned)f2bf(pfb.z) | ((unsigned)f2bf(pfb.w) << 16);
            *(uint4*)&buf[(tt * 16 + row) * XWP + k] = pv;
        } else {
            const int flat = tid * 16;
            const int tt = flat >> 11, row = (flat >> 7) & 15, k = flat & 127;
            *(uint4*)&buf[(tt * 16 + row) * XWP + k]     = pf0;
            *(uint4*)&buf[(tt * 16 + row) * XWP + k + 8] = pf1;
        }
        bar_lds();
        // ---- issue prefetch for next window ----
        const int wst = tw + WT;
        if (wst < TT) {
            if (!IS_L1 && (wst & (CH - 1)) == 0) wait_flag(&f_in[wst >> 4]);
            if (IS_L1) {
                const float* x = (const float*)xin_;
                const int flat = tid * 8;
                const int tt = flat >> 10, row = (flat >> 6) & 15, k = flat & 63;
                const float* s = x + (((size_t)(bg * 16 + row)) * TT + wst + tt) * FF + k;
                pfa = *(const float4*)s; pfb = *(const float4*)(s + 4);
            } else {
                const unsigned short* o1 = (const unsigned short*)xin_;
                const int flat = tid * 16;
                const int tt = flat >> 11, row = (flat >> 7) & 15, k = flat & 127;
                const unsigned short* s = o1 + (((size_t)(bg * 16 + row)) * TT + wst + tt) * HH + k;
                pf0 = *(const uint4*)s; pf1 = *(const uint4*)(s + 8);
            }
        }

        const unsigned short* wbase = xw + ((tw >> 2) & 1) * XBUF;

        #pragma unroll
        for (int half = 0; half < 2; half++) {
            // ---- x-burst: gate partials for the next 2 steps (no h dep) ----
            f32x4 xacc[2][4];
            #pragma unroll
            for (int ts = 0; ts < 2; ts++) {
                #pragma unroll
                for (int j = 0; j < 4; j++)
                    xacc[ts][j] = (f32x4){bv[j], bv[j], bv[j], bv[j]};
                const unsigned short* abase = wbase
                    + ((half * 2 + ts) * 16 + lm) * XWP + kb * 8;
                #pragma unroll
                for (int kt = 0; kt < XKT; kt++) {
                    const short8 a = *(const short8*)(abase + kt * 32);
                    xacc[ts][0] = __builtin_amdgcn_mfma_f32_16x16x32_bf16(a, bf[0][kt], xacc[ts][0], 0, 0, 0);
                    xacc[ts][1] = __builtin_amdgcn_mfma_f32_16x16x32_bf16(a, bf[1][kt], xacc[ts][1], 0, 0, 0);
                    xacc[ts][2] = __builtin_amdgcn_mfma_f32_16x16x32_bf16(a, bf[2][kt], xacc[ts][2], 0, 0, 0);
                    xacc[ts][3] = __builtin_amdgcn_mfma_f32_16x16x32_bf16(a, bf[3][kt], xacc[ts][3], 0, 0, 0);
                }
            }
            // ---- 2 serial steps: h-MFMA only + epilogue ----
            #pragma unroll
            for (int ts = 0; ts < 2; ts++) {
                const int tl = tw + half * 2 + ts;            // tl&1 == ts&1
                const unsigned short* hbase = hb + (ts & 1) * HBSZ + lm * HBP + kb * 8;

                f32x4 a0 = xacc[ts][0], a1 = xacc[ts][1];
                f32x4 a2 = xacc[ts][2], a3 = xacc[ts][3];
                #pragma unroll
                for (int hkt = 0; hkt < HKT; hkt++) {
                    const short8 a = *(const short8*)(hbase + hkt * 32);
                    a0 = __builtin_amdgcn_mfma_f32_16x16x32_bf16(a, bf[0][XKT + hkt], a0, 0, 0, 0);
                    a1 = __builtin_amdgcn_mfma_f32_16x16x32_bf16(a, bf[1][XKT + hkt], a1, 0, 0, 0);
                    a2 = __builtin_amdgcn_mfma_f32_16x16x32_bf16(a, bf[2][XKT + hkt], a2, 0, 0, 0);
                    a3 = __builtin_amdgcn_mfma_f32_16x16x32_bf16(a, bf[3][XKT + hkt], a3, 0, 0, 0);
                }

                // ---- in-lane epilogue: unit u, rows kb*4+r ----
                #pragma unroll
                for (int r = 0; r < 4; r++) {
                    const float iv = sigf(a0[r]);
                    const float fv = sigf(a1[r]);
                    const float gv = tanhfast(a2[r]);
                    const float ov = sigf(a3[r]);
                    c[r] = fv * c[r] + iv * gv;
                    const float h = ov * tanhfast(c[r]);
                    hlast[r] = h;
                    const unsigned short h16 = f2bf(h);
                    hb[((ts + 1) & 1) * HBSZ + (kb * 4 + r) * HBP + u] = h16;
                    if (IS_L1)
                        out1[(((size_t)(bg * 16 + kb * 4 + r)) * TT + tl) * HH + u] = h16;
                }

                if (IS_L1 && (tl & (CH - 1)) == (CH - 1)) {
                    set_flag(&f_out[tl >> 4]);   // fence + barrier + flag (per chunk)
                } else {
                    bar_lds();                   // publish h for next step
                }
            }
        }
    }

    if (!IS_L1) {
        #pragma unroll
        for (int r = 0; r < 4; r++)
            h2s[((size_t)(bg * 16 + kb * 4 + r)) * HH + u] = hlast[r];
    }
}

// bid 0-31: layer-1 scan (producer). bid 32-63: layer-2 scan (consumer).
// bid and bid+32 share bid%8 -> same XCD for out1 L2-cache locality.
__global__ __launch_bounds__(512, 1) void lstm_pipe(
    const float* __restrict__ x,
    const float* __restrict__ w1_ih, const float* __restrict__ w1_hh,
    const float* __restrict__ b1_ih, const float* __restrict__ b1_hh,
    const float* __restrict__ w2_ih, const float* __restrict__ w2_hh,
    const float* __restrict__ b2_ih, const float* __restrict__ b2_hh,
    unsigned short* __restrict__ out1, float* __restrict__ h2s,
    int* __restrict__ flags)
{
    __shared__ __align__(16) unsigned short xw[2 * WT * 16 * (HH + 8)]; // 34816 B (L2 max)
    __shared__ __align__(16) unsigned short hb[2 * HBSZ];               //  8704 B
    const int bid = blockIdx.x;
    if (bid < 32)
        layer_scan<FF, true >(x, w1_ih, w1_hh, b1_ih, b1_hh, out1, nullptr,
                              nullptr, &flags[bid * 32], bid, xw, hb);
    else
        layer_scan<HH, false>(out1, w2_ih, w2_hh, b2_ih, b2_hh, nullptr, h2s,
                              &flags[(bid - 32) * 32], nullptr, bid - 32, xw, hb);
}

__global__ void final_kernel(const float* __restrict__ h2s,
                             const float* __restrict__ w_fc,
                             const float* __restrict__ b_fc,
                             float* __restrict__ out)
{
    const int idx = blockIdx.x * blockDim.x + threadIdx.x;
    if (idx >= BB * NCLS) return;
    const int b = idx / NCLS, cls = idx % NCLS;
    const float* hp = h2s + (size_t)b * HH;
    const float* wp = w_fc + (size_t)cls * HH;
    float acc = b_fc[cls];
    #pragma unroll 8
    for (int k = 0; k < HH; k++) acc += hp[k] * wp[k];
    out[idx] = sigf(acc);
}

extern "C" void kernel_launch(void* const* d_in, const int* in_sizes, int n_in,
                              void* d_out, int out_size, void* d_ws, size_t ws_size,
                              hipStream_t stream)
{
    const float* x     = (const float*)d_in[0];
    const float* w1_ih = (const float*)d_in[1];
    const float* w1_hh = (const float*)d_in[2];
    const float* b1_ih = (const float*)d_in[3];
    const float* b1_hh = (const float*)d_in[4];
    const float* w2_ih = (const float*)d_in[5];
    const float* w2_hh = (const float*)d_in[6];
    const float* b2_ih = (const float*)d_in[7];
    const float* b2_hh = (const float*)d_in[8];
    const float* w_fc  = (const float*)d_in[9];
    const float* b_fc  = (const float*)d_in[10];
    float* out = (float*)d_out;

    // workspace: [h2s fp32 256KB | flags 4KB | out1 bf16 67MB]
    char* ws = (char*)d_ws;
    float* h2s = (float*)ws;                 ws += (size_t)BB * HH * sizeof(float);
    int* flags = (int*)ws;                   ws += 32 * 32 * sizeof(int);
    unsigned short* out1 = (unsigned short*)ws;

    hipMemsetAsync(flags, 0, 32 * 32 * sizeof(int), stream);
    lstm_pipe<<<64, 512, 0, stream>>>(x, w1_ih, w1_hh, b1_ih, b1_hh,
                                      w2_ih, w2_hh, b2_ih, b2_hh,
                                      out1, h2s, flags);
    final_kernel<<<(BB * NCLS + 255) / 256, 256, 0, stream>>>(h2s, w_fc, b_fc, out);
}

// Round 6
// 777.736 us; speedup vs baseline: 1.7752x; 1.1375x over previous
//
#include <hip/hip_runtime.h>

#define BB 512
#define TT 512
#define FF 64
#define HH 128
#define NCLS 10
#define WT 4            // LDS staging window (steps)
#define CH 16           // producer->consumer chunk (steps)
#define HBP 136         // padded h row (shorts): 272 B, 16B-divisible
#define HBSZ (16 * HBP)

typedef __attribute__((ext_vector_type(8))) short short8;
typedef __attribute__((ext_vector_type(4))) float f32x4;

#define LOG2E   1.4426950408889634f
#define NLOG2E  (-1.4426950408889634f)
#define N2LOG2E (-2.8853900817779268f)

__device__ __forceinline__ unsigned short f2bf(float f) {
    union { float f; unsigned u; } v; v.f = f;
    unsigned r = v.u + 0x7FFFu + ((v.u >> 16) & 1u);   // RNE
    return (unsigned short)(r >> 16);
}

// LDS-only barrier: drain lgkmcnt + raw s_barrier (no vmcnt drain).
__device__ __forceinline__ void bar_lds() {
    asm volatile("s_waitcnt lgkmcnt(0)" ::: "memory");
    __builtin_amdgcn_s_barrier();
    asm volatile("" ::: "memory");
}

// ---- flag protocol --------------------------------------------------------
__device__ __forceinline__ void wait_flag(int* f) {
    if (threadIdx.x == 0) {
        while (__hip_atomic_load(f, __ATOMIC_ACQUIRE, __HIP_MEMORY_SCOPE_AGENT) == 0)
            __builtin_amdgcn_s_sleep(2);
    }
    __syncthreads();
    (void)__hip_atomic_load(f, __ATOMIC_ACQUIRE, __HIP_MEMORY_SCOPE_AGENT);
}
__device__ __forceinline__ void set_flag(int* f) {
    __threadfence();
    __syncthreads();   // doubles as the boundary barrier on chunk-end steps
    if (threadIdx.x == 0)
        __hip_atomic_fetch_add(f, 1, __ATOMIC_RELEASE, __HIP_MEMORY_SCOPE_AGENT);
}

// ---------------------------------------------------------------------------
// R6 = R5 with the commit/prefetch off-by-one fixed.
// Pipeline invariant: at window tw's step 3, pf registers hold W(tw+WT) data.
//   - preamble: PREFETCH(0), COMMIT(0), PREFETCH(WT)
//   - step 3:   COMMIT(W(tw+WT) buffer)  [consumes regs]
//               PREFETCH(tw+2*WT)        [refills regs for next window's commit]
// L2 flag wait keyed to the PREFETCH target's chunk crossing.
// Everything else as R5: fused-exp activations (8 trans/row), cvt_pk bf16
// packing, merged window barrier, x-burst pipelined one step ahead in regs.
// ---------------------------------------------------------------------------
template<int XW, bool IS_L1>
__device__ void layer_scan(
    const void* __restrict__ xin_,
    const float* __restrict__ w_ih, const float* __restrict__ w_hh,
    const float* __restrict__ b_ih, const float* __restrict__ b_hh,
    unsigned short* __restrict__ out1,   // L1: h stream out (bf16)
    float* __restrict__ h2s,             // L2: final h out (fp32)
    int* __restrict__ f_in,              // L2: per-chunk input flags
    int* __restrict__ f_out,             // L1: per-chunk done flags
    int bg, unsigned short* xw, unsigned short* hb)
{
    const int tid = threadIdx.x;
    const int w = tid >> 6, l = tid & 63, lm = l & 15, kb = l >> 4;
    const int u = w * 16 + lm;           // owned hidden unit
    constexpr int KT  = (XW + HH) / 32;  // 6 (L1) / 8 (L2)
    constexpr int XKT = XW / 32;         // 2 / 4
    constexpr int HKT = HH / 32;         // 4
    constexpr int XWP = XW + 8;          // padded LDS row (shorts)
    constexpr int XBUF = WT * 16 * XWP;  // one window buffer (shorts)

    // --- stationary B fragments + bias: gate g = j*128 + u; x-kts then h-kts ---
    short8 bf[4][KT];
    float bv[4];
    #pragma unroll
    for (int j = 0; j < 4; j++) {
        const int g = j * 128 + u;
        bv[j] = b_ih[g] + b_hh[g];
        #pragma unroll
        for (int kt = 0; kt < KT; kt++) {
            const int k0 = kt * 32 + kb * 8;
            const float* s = (k0 < XW) ? (w_ih + (size_t)g * XW + k0)
                                       : (w_hh + (size_t)g * HH + (k0 - XW));
            short8 t;
            #pragma unroll
            for (int q = 0; q < 8; q++) t[q] = (short)f2bf(s[q]);
            bf[j][kt] = t;
        }
    }

    for (int i = tid; i < 2 * HBSZ; i += 512) hb[i] = 0;

    float c[4] = {0.f, 0.f, 0.f, 0.f}, hlast[4] = {0.f, 0.f, 0.f, 0.f};

    float4 pfa, pfb;     // L1: 8 fp32
    uint4  pf0, pf1;     // L2: 16 bf16

    // ---- helper lambdas (all inlined) ----
    auto PREFETCH = [&](int t0) {
        if (IS_L1) {
            const float* x = (const float*)xin_;
            const int flat = tid * 8;
            const int tt2 = flat >> 10, row = (flat >> 6) & 15, k = flat & 63;
            const float* s = x + (((size_t)(bg * 16 + row)) * TT + t0 + tt2) * FF + k;
            pfa = *(const float4*)s; pfb = *(const float4*)(s + 4);
        } else {
            const unsigned short* o1 = (const unsigned short*)xin_;
            const int flat = tid * 16;
            const int tt2 = flat >> 11, row = (flat >> 7) & 15, k = flat & 127;
            const unsigned short* s = o1 + (((size_t)(bg * 16 + row)) * TT + t0 + tt2) * HH + k;
            pf0 = *(const uint4*)s; pf1 = *(const uint4*)(s + 8);
        }
    };
    auto COMMIT = [&](int bufidx) {
        unsigned short* buf = xw + bufidx * XBUF;
        if (IS_L1) {
            const int flat = tid * 8;
            const int tt2 = flat >> 10, row = (flat >> 6) & 15, k = flat & 63;
            uint4 pv;
            pv.x = (unsigned)f2bf(pfa.x) | ((unsigned)f2bf(pfa.y) << 16);
            pv.y = (unsigned)f2bf(pfa.z) | ((unsigned)f2bf(pfa.w) << 16);
            pv.z = (unsigned)f2bf(pfb.x) | ((unsigned)f2bf(pfb.y) << 16);
            pv.w = (unsigned)f2bf(pfb.z) | ((unsigned)f2bf(pfb.w) << 16);
            *(uint4*)&buf[(tt2 * 16 + row) * XWP + k] = pv;
        } else {
            const int flat = tid * 16;
            const int tt2 = flat >> 11, row = (flat >> 7) & 15, k = flat & 127;
            *(uint4*)&buf[(tt2 * 16 + row) * XWP + k]     = pf0;
            *(uint4*)&buf[(tt2 * 16 + row) * XWP + k + 8] = pf1;
        }
    };
    auto XB = [&](f32x4 (&dst)[4], const unsigned short* wbase, int ts) {
        #pragma unroll
        for (int j = 0; j < 4; j++) dst[j] = (f32x4){bv[j], bv[j], bv[j], bv[j]};
        const unsigned short* ab = wbase + (ts * 16 + lm) * XWP + kb * 8;
        #pragma unroll
        for (int kt = 0; kt < XKT; kt++) {
            const short8 a = *(const short8*)(ab + kt * 32);
            dst[0] = __builtin_amdgcn_mfma_f32_16x16x32_bf16(a, bf[0][kt], dst[0], 0, 0, 0);
            dst[1] = __builtin_amdgcn_mfma_f32_16x16x32_bf16(a, bf[1][kt], dst[1], 0, 0, 0);
            dst[2] = __builtin_amdgcn_mfma_f32_16x16x32_bf16(a, bf[2][kt], dst[2], 0, 0, 0);
            dst[3] = __builtin_amdgcn_mfma_f32_16x16x32_bf16(a, bf[3][kt], dst[3], 0, 0, 0);
        }
    };
    auto HM = [&](f32x4 (&a)[4], int par) {
        const unsigned short* hbase = hb + par * HBSZ + lm * HBP + kb * 8;
        #pragma unroll
        for (int kt = 0; kt < HKT; kt++) {
            const short8 av = *(const short8*)(hbase + kt * 32);
            a[0] = __builtin_amdgcn_mfma_f32_16x16x32_bf16(av, bf[0][XKT + kt], a[0], 0, 0, 0);
            a[1] = __builtin_amdgcn_mfma_f32_16x16x32_bf16(av, bf[1][XKT + kt], a[1], 0, 0, 0);
            a[2] = __builtin_amdgcn_mfma_f32_16x16x32_bf16(av, bf[2][XKT + kt], a[2], 0, 0, 0);
            a[3] = __builtin_amdgcn_mfma_f32_16x16x32_bf16(av, bf[3][XKT + kt], a[3], 0, 0, 0);
        }
    };
    auto EPI = [&](f32x4 (&a)[4], int tl) {
        float hv[4];
        #pragma unroll
        for (int r = 0; r < 4; r++) {
            // f = sigmoid(a1)
            const float ef = __builtin_amdgcn_exp2f(NLOG2E * a[1][r]);
            const float fv = __builtin_amdgcn_rcpf(1.f + ef);
            // i*g = (1-eg) / ((1+ea)(1+eg))   [fused sigmoid*tanh]
            const float ea = __builtin_amdgcn_exp2f(NLOG2E * a[0][r]);
            const float g2 = fmaxf(a[2][r], -30.f);              // NaN guard
            const float eg = __builtin_amdgcn_exp2f(N2LOG2E * g2);
            const float ig = (1.f - eg) * __builtin_amdgcn_rcpf((1.f + ea) * (1.f + eg));
            c[r] = fv * c[r] + ig;
            // h = o*tanh(c) = (1-ec) / ((1+eo)(1+ec))
            const float eo = __builtin_amdgcn_exp2f(NLOG2E * a[3][r]);
            const float cc = fmaxf(c[r], -30.f);                 // NaN guard
            const float ec = __builtin_amdgcn_exp2f(N2LOG2E * cc);
            hv[r] = (1.f - ec) * __builtin_amdgcn_rcpf((1.f + eo) * (1.f + ec));
            hlast[r] = hv[r];
        }
        unsigned p01, p23;   // packed bf16 pairs, RNE
        asm("v_cvt_pk_bf16_f32 %0, %1, %2" : "=v"(p01) : "v"(hv[0]), "v"(hv[1]));
        asm("v_cvt_pk_bf16_f32 %0, %1, %2" : "=v"(p23) : "v"(hv[2]), "v"(hv[3]));
        const unsigned short h0 = (unsigned short)(p01 & 0xffffu);
        const unsigned short h1 = (unsigned short)(p01 >> 16);
        const unsigned short h2 = (unsigned short)(p23 & 0xffffu);
        const unsigned short h3 = (unsigned short)(p23 >> 16);
        unsigned short* hw = hb + ((tl + 1) & 1) * HBSZ + (kb * 4) * HBP + u;
        hw[0] = h0; hw[HBP] = h1; hw[2 * HBP] = h2; hw[3 * HBP] = h3;
        if (IS_L1) {
            unsigned short* op = out1 + (((size_t)(bg * 16 + kb * 4)) * TT + tl) * HH + u;
            op[0] = h0;
            op[(size_t)TT * HH] = h1;
            op[(size_t)2 * TT * HH] = h2;
            op[(size_t)3 * TT * HH] = h3;
        }
    };

    // ---- preamble: window-0 prefetch+commit, then prefetch window 1 ----
    if (!IS_L1) wait_flag(&f_in[0]);   // covers steps 0..15 (chunk 0)
    PREFETCH(0);
    COMMIT(0);
    PREFETCH(WT);                      // invariant: regs hold W(tw+WT) at step 3
    bar_lds();

    for (int tw = 0; tw < TT; tw += WT) {
        const unsigned short* wbase = xw + ((tw >> 2) & 1) * XBUF;
        const int wst = tw + WT;           // next window start (commit target)
        const int pnext = tw + 2 * WT;     // prefetch target (refills regs)
        f32x4 xc0[4], xc1[4], xn0[4], xn1[4];

        // ---- step 0: own x-burst + next step's burst live in this span ----
        XB(xc0, wbase, 0);
        XB(xc1, wbase, 1);              // hides under epi0
        HM(xc0, 0);
        EPI(xc0, tw + 0);
        bar_lds();
        // ---- step 1 ----
        XB(xn0, wbase, 2);              // hides under epi1
        HM(xc1, 1);
        EPI(xc1, tw + 1);
        bar_lds();
        // ---- step 2 ----
        XB(xn1, wbase, 3);              // hides under epi2
        HM(xn0, 0);
        EPI(xn0, tw + 2);
        bar_lds();
        // ---- step 3: + window commit & prefetch (merged boundary) ----
        HM(xn1, 1);
        if (wst < TT) COMMIT((wst >> 2) & 1);   // regs = W(wst); other buffer dead here
        EPI(xn1, tw + 3);
        if (pnext < TT) {
            if (!IS_L1 && (pnext & (CH - 1)) == 0) wait_flag(&f_in[pnext >> 4]);
            PREFETCH(pnext);            // consumed at next window's step-3 commit
        }
        if (IS_L1 && ((tw + 3) & (CH - 1)) == (CH - 1)) {
            set_flag(&f_out[(tw + 3) >> 4]);    // fence + barrier + flag
        } else {
            bar_lds();                          // boundary barrier (covers commit)
        }
    }

    if (!IS_L1) {
        #pragma unroll
        for (int r = 0; r < 4; r++)
            h2s[((size_t)(bg * 16 + kb * 4 + r)) * HH + u] = hlast[r];
    }
}

// bid 0-31: layer-1 scan (producer). bid 32-63: layer-2 scan (consumer).
// bid and bid+32 share bid%8 -> same XCD for out1 L2-cache locality.
__global__ __launch_bounds__(512, 1) void lstm_pipe(
    const float* __restrict__ x,
    const float* __restrict__ w1_ih, const float* __restrict__ w1_hh,
    const float* __restrict__ b1_ih, const float* __restrict__ b1_hh,
    const float* __restrict__ w2_ih, const float* __restrict__ w2_hh,
    const float* __restrict__ b2_ih, const float* __restrict__ b2_hh,
    unsigned short* __restrict__ out1, float* __restrict__ h2s,
    int* __restrict__ flags)
{
    __shared__ __align__(16) unsigned short xw[2 * WT * 16 * (HH + 8)]; // 34816 B (L2 max)
    __shared__ __align__(16) unsigned short hb[2 * HBSZ];               //  8704 B
    const int bid = blockIdx.x;
    if (bid < 32)
        layer_scan<FF, true >(x, w1_ih, w1_hh, b1_ih, b1_hh, out1, nullptr,
                              nullptr, &flags[bid * 32], bid, xw, hb);
    else
        layer_scan<HH, false>(out1, w2_ih, w2_hh, b2_ih, b2_hh, nullptr, h2s,
                              &flags[(bid - 32) * 32], nullptr, bid - 32, xw, hb);
}

__global__ void final_kernel(const float* __restrict__ h2s,
                             const float* __restrict__ w_fc,
                             const float* __restrict__ b_fc,
                             float* __restrict__ out)
{
    const int idx = blockIdx.x * blockDim.x + threadIdx.x;
    if (idx >= BB * NCLS) return;
    const int b = idx / NCLS, cls = idx % NCLS;
    const float* hp = h2s + (size_t)b * HH;
    const float* wp = w_fc + (size_t)cls * HH;
    float acc = b_fc[cls];
    #pragma unroll 8
    for (int k = 0; k < HH; k++) acc += hp[k] * wp[k];
    const float e = __builtin_amdgcn_exp2f(NLOG2E * acc);
    out[idx] = __builtin_amdgcn_rcpf(1.0f + e);
}

extern "C" void kernel_launch(void* const* d_in, const int* in_sizes, int n_in,
                              void* d_out, int out_size, void* d_ws, size_t ws_size,
                              hipStream_t stream)
{
    const float* x     = (const float*)d_in[0];
    const float* w1_ih = (const float*)d_in[1];
    const float* w1_hh = (const float*)d_in[2];
    const float* b1_ih = (const float*)d_in[3];
    const float* b1_hh = (const float*)d_in[4];
    const float* w2_ih = (const float*)d_in[5];
    const float* w2_hh = (const float*)d_in[6];
    const float* b2_ih = (const float*)d_in[7];
    const float* b2_hh = (const float*)d_in[8];
    const float* w_fc  = (const float*)d_in[9];
    const float* b_fc  = (const float*)d_in[10];
    float* out = (float*)d_out;

    // workspace: [h2s fp32 256KB | flags 4KB | out1 bf16 67MB]
    char* ws = (char*)d_ws;
    float* h2s = (float*)ws;                 ws += (size_t)BB * HH * sizeof(float);
    int* flags = (int*)ws;                   ws += 32 * 32 * sizeof(int);
    unsigned short* out1 = (unsigned short*)ws;

    hipMemsetAsync(flags, 0, 32 * 32 * sizeof(int), stream);
    lstm_pipe<<<64, 512, 0, stream>>>(x, w1_ih, w1_hh, b1_ih, b1_hh,
                                      w2_ih, w2_hh, b2_ih, b2_hh,
                                      out1, h2s, flags);
    final_kernel<<<(BB * NCLS + 255) / 256, 256, 0, stream>>>(h2s, w_fc, b_fc, out);
}